// Round 3
// baseline (360.732 us; speedup 1.0000x reference)
//
#include <hip/hip_runtime.h>

#define B_ROWS 524288
#define C_CLS  128
#define CONF_PEN 0.5f
#define PROB_THRESH 0.2f
#define WEIGHT_THRESH 1.0f

#define BLOCKS 2048
#define THREADS 256
#define WAVES_PER_BLOCK (THREADS / 64)
#define PAIRS 4   // row-pairs in flight per wave per iteration (8 rows/iter)
#define NWAVES (BLOCKS * WAVES_PER_BLOCK)     // 8192
#define ROWS_PER_SWEEP (NWAVES * 2 * PAIRS)   // 65536
#define ITERS (B_ROWS / ROWS_PER_SWEEP)       // 8, exact

// Butterfly sum step on the VALU pipe (DPP) instead of the DS pipe.
// Valid because after steps xor1/xor2 all lanes of a quad are equal, so
// row_half_mirror (i^7 source) delivers the i^4 quad's value, and after
// that row_mirror (i^15 source) delivers the i^8 group's value.
template <int CTRL>
__device__ __forceinline__ float dpp_add(float x) {
    int y = __builtin_amdgcn_update_dpp(0, __float_as_int(x), CTRL, 0xF, 0xF, true);
    return x + __int_as_float(y);
}

__device__ __forceinline__ float sum32(float s) {
    s = dpp_add<0xB1>(s);    // quad_perm {1,0,3,2}  : + lane^1
    s = dpp_add<0x4E>(s);    // quad_perm {2,3,0,1}  : + lane^2
    s = dpp_add<0x141>(s);   // row_half_mirror      : + lane^4 (quads uniform)
    s = dpp_add<0x140>(s);   // row_mirror           : + lane^8 (octs uniform)
    s += __shfl_xor(s, 16);  // cross 16 within the 32-lane half (DS, 1 op)
    return s;
}

// d_ws layout: per-block partials, partial[3*b + {0,1,2}] = {base_sum, pen_sum, count}
__global__ __launch_bounds__(THREADS, 4) void afl_main(
    const float* __restrict__ outputs,
    const int* __restrict__ labels,
    const float* __restrict__ cw,
    float* __restrict__ partial) {

    const int lane = threadIdx.x & 63;
    const int wave = threadIdx.x >> 6;
    const int half = lane >> 5;          // which row of each pair
    const int sub  = lane & 31;          // lane within 32-lane half
    const int gwave = blockIdx.x * WAVES_PER_BLOCK + wave;

    float base_acc = 0.0f;
    float pen_acc  = 0.0f;
    float cnt_acc  = 0.0f;

    const int row0 = gwave * (2 * PAIRS);

    #pragma unroll 2
    for (int it = 0; it < ITERS; ++it) {
        const int base = row0 + it * ROWS_PER_SWEEP;

        float4 v[PAIRS];
        int    lab[PAIRS];
        float4 w[PAIRS];

        // --- issue all row loads + label loads up front (ILP) ---
        #pragma unroll
        for (int j = 0; j < PAIRS; ++j) {
            const int row = base + 2 * j + half;
            v[j]   = ((const float4*)(outputs + (size_t)row * C_CLS))[sub];
            lab[j] = labels[row];
        }
        // --- dependent confusion-weight row gathers (64 KB table, L2-resident) ---
        #pragma unroll
        for (int j = 0; j < PAIRS; ++j) {
            w[j] = ((const float4*)(cw + (size_t)lab[j] * C_CLS))[sub];
        }

        // --- exp (no max-subtraction: |logit| <= ~30, e^30 = 4e12, safe in fp32) ---
        float e0[PAIRS], e1[PAIRS], e2[PAIRS], e3[PAIRS], s[PAIRS];
        #pragma unroll
        for (int j = 0; j < PAIRS; ++j) {
            e0[j] = __expf(v[j].x);
            e1[j] = __expf(v[j].y);
            e2[j] = __expf(v[j].z);
            e3[j] = __expf(v[j].w);
            s[j]  = (e0[j] + e1[j]) + (e2[j] + e3[j]);
        }

        // --- 32-lane sum reduction, 4 DPP adds + 1 shuffle each, interleaved ---
        #pragma unroll
        for (int j = 0; j < PAIRS; ++j)
            s[j] = sum32(s[j]);

        #pragma unroll
        for (int j = 0; j < PAIRS; ++j) {
            const float logZ  = __logf(s[j]);
            const float inv_s = 1.0f / s[j];

            // base CE: the lane holding the label column contributes logZ - x_label
            if ((lab[j] >> 2) == sub) {
                const float xl = (lab[j] & 2) ? ((lab[j] & 1) ? v[j].w : v[j].z)
                                              : ((lab[j] & 1) ? v[j].y : v[j].x);
                base_acc += logZ - xl;
            }

            // confusion penalty
            const int c0 = 4 * sub;
            float p;
            p = e0[j] * inv_s;
            if (c0 + 0 != lab[j] && w[j].x > WEIGHT_THRESH && p > PROB_THRESH) { pen_acc += w[j].x * p; cnt_acc += 1.0f; }
            p = e1[j] * inv_s;
            if (c0 + 1 != lab[j] && w[j].y > WEIGHT_THRESH && p > PROB_THRESH) { pen_acc += w[j].y * p; cnt_acc += 1.0f; }
            p = e2[j] * inv_s;
            if (c0 + 2 != lab[j] && w[j].z > WEIGHT_THRESH && p > PROB_THRESH) { pen_acc += w[j].z * p; cnt_acc += 1.0f; }
            p = e3[j] * inv_s;
            if (c0 + 3 != lab[j] && w[j].w > WEIGHT_THRESH && p > PROB_THRESH) { pen_acc += w[j].w * p; cnt_acc += 1.0f; }
        }
    }

    // --- full-wave reduction of the three accumulators ---
    #pragma unroll
    for (int off = 32; off >= 1; off >>= 1) {
        base_acc += __shfl_xor(base_acc, off);
        pen_acc  += __shfl_xor(pen_acc, off);
        cnt_acc  += __shfl_xor(cnt_acc, off);
    }

    __shared__ float s_base[WAVES_PER_BLOCK];
    __shared__ float s_pen [WAVES_PER_BLOCK];
    __shared__ float s_cnt [WAVES_PER_BLOCK];
    if (lane == 0) {
        s_base[wave] = base_acc;
        s_pen [wave] = pen_acc;
        s_cnt [wave] = cnt_acc;
    }
    __syncthreads();
    if (threadIdx.x == 0) {
        float b = 0.0f, pn = 0.0f, c = 0.0f;
        #pragma unroll
        for (int i = 0; i < WAVES_PER_BLOCK; ++i) {
            b += s_base[i]; pn += s_pen[i]; c += s_cnt[i];
        }
        partial[3 * blockIdx.x + 0] = b;
        partial[3 * blockIdx.x + 1] = pn;
        partial[3 * blockIdx.x + 2] = c;
    }
}

__global__ __launch_bounds__(256) void afl_finalize(
    const float* __restrict__ partial, float* __restrict__ out) {
    float b = 0.0f, pn = 0.0f, c = 0.0f;
    for (int i = threadIdx.x; i < BLOCKS; i += 256) {
        b  += partial[3 * i + 0];
        pn += partial[3 * i + 1];
        c  += partial[3 * i + 2];
    }
    #pragma unroll
    for (int off = 32; off >= 1; off >>= 1) {
        b  += __shfl_xor(b, off);
        pn += __shfl_xor(pn, off);
        c  += __shfl_xor(c, off);
    }
    __shared__ float sb[4], sp[4], sc[4];
    const int wave = threadIdx.x >> 6;
    if ((threadIdx.x & 63) == 0) { sb[wave] = b; sp[wave] = pn; sc[wave] = c; }
    __syncthreads();
    if (threadIdx.x == 0) {
        b  = sb[0] + sb[1] + sb[2] + sb[3];
        pn = sp[0] + sp[1] + sp[2] + sp[3];
        c  = sc[0] + sc[1] + sc[2] + sc[3];
        const float penalty = (c > 0.0f) ? (pn / c) : 0.0f;
        out[0] = b * (1.0f / (float)B_ROWS) + CONF_PEN * penalty;
    }
}

extern "C" void kernel_launch(void* const* d_in, const int* in_sizes, int n_in,
                              void* d_out, int out_size, void* d_ws, size_t ws_size,
                              hipStream_t stream) {
    const float* outputs = (const float*)d_in[0];
    const int*   labels  = (const int*)d_in[1];
    const float* cw      = (const float*)d_in[2];
    float* out = (float*)d_out;
    float* partial = (float*)d_ws;

    afl_main<<<BLOCKS, THREADS, 0, stream>>>(outputs, labels, cw, partial);
    afl_finalize<<<1, 256, 0, stream>>>(partial, out);
}

// Round 4
// 360.529 us; speedup vs baseline: 1.0006x; 1.0006x over previous
//
#include <hip/hip_runtime.h>

#define B_ROWS 524288
#define C_CLS  128
#define CONF_PEN 0.5f
#define PROB_THRESH 0.2f
#define WEIGHT_THRESH 1.0f

#define BLOCKS 2048
#define THREADS 256
#define WPB (THREADS / 64)
#define PAIRS 4                        // row-pairs per wave per iteration (8 rows)
#define NWAVES (BLOCKS * WPB)          // 8192
#define SWEEP (NWAVES * 2 * PAIRS)     // 65536 rows per sweep
#define ITERS (B_ROWS / SWEEP)         // 8, exact

// Butterfly sum on the VALU pipe via DPP (xor16 via one shuffle).
template <int CTRL>
__device__ __forceinline__ float dpp_add(float x) {
    int y = __builtin_amdgcn_update_dpp(0, __float_as_int(x), CTRL, 0xF, 0xF, true);
    return x + __int_as_float(y);
}
__device__ __forceinline__ float sum32(float s) {
    s = dpp_add<0xB1>(s);    // + lane^1
    s = dpp_add<0x4E>(s);    // + lane^2
    s = dpp_add<0x141>(s);   // + lane^4 (row_half_mirror; quads uniform)
    s = dpp_add<0x140>(s);   // + lane^8 (row_mirror; octs uniform)
    s += __shfl_xor(s, 16);
    return s;
}

// cwp[r][c] = (c != r && cw[r][c] > 1.0) ? cw[r][c] : 0
// Folds the (cls != label) and (w > thresh) mask terms into the table once.
__global__ __launch_bounds__(THREADS) void afl_prep(
    const float* __restrict__ cw, float* __restrict__ cwp) {
    const int i = blockIdx.x * THREADS + threadIdx.x;   // 64 blocks * 256 = 16384
    const int r = i >> 7, c = i & 127;
    const float w = cw[i];
    cwp[i] = (c != r && w > WEIGHT_THRESH) ? w : 0.0f;
}

// d_ws layout: partial[3*b+{0,1,2}] per block; cwp table at float offset 16384.
__global__ __launch_bounds__(THREADS, 3) void afl_main(
    const float* __restrict__ outputs,
    const int* __restrict__ labels,
    const float* __restrict__ cwp,
    float* __restrict__ partial) {

    const int lane = threadIdx.x & 63;
    const int wave = threadIdx.x >> 6;
    const int half = lane >> 5;
    const int sub  = lane & 31;
    const int gwave = blockIdx.x * WPB + wave;
    const int row0  = gwave * (2 * PAIRS);

    float base_acc = 0.0f, pen_acc = 0.0f, cnt_acc = 0.0f;

    // ---- pipeline prologue: labels for it=0 and it=1, v-loads for it=0 ----
    int    labc[PAIRS], labn[PAIRS];
    float4 vc[PAIRS];
    #pragma unroll
    for (int j = 0; j < PAIRS; ++j)
        labc[j] = labels[row0 + 2 * j + half];
    #pragma unroll
    for (int j = 0; j < PAIRS; ++j)
        labn[j] = labels[row0 + SWEEP + 2 * j + half];
    #pragma unroll
    for (int j = 0; j < PAIRS; ++j)
        vc[j] = ((const float4*)(outputs + (size_t)(row0 + 2 * j + half) * C_CLS))[sub];

    for (int it = 0; it < ITERS; ++it) {            // rolled: rotation = register copies
        const int base = row0 + it * SWEEP;

        // current-iter w gathers (labc loaded >=1 iter ago; latency hidden by exp prefix)
        float4 w[PAIRS];
        #pragma unroll
        for (int j = 0; j < PAIRS; ++j)
            w[j] = ((const float4*)(cwp + (size_t)labc[j] * C_CLS))[sub];

        // next-iter v prefetch + labels two ahead
        float4 vn[PAIRS];
        int    lab2[PAIRS];
        if (it + 1 < ITERS) {
            #pragma unroll
            for (int j = 0; j < PAIRS; ++j)
                vn[j] = ((const float4*)(outputs + (size_t)(base + SWEEP + 2 * j + half) * C_CLS))[sub];
        }
        if (it + 2 < ITERS) {
            #pragma unroll
            for (int j = 0; j < PAIRS; ++j)
                lab2[j] = labels[base + 2 * SWEEP + 2 * j + half];
        }

        // ---- compute on current iteration (vc, w, labc) ----
        #pragma unroll
        for (int j = 0; j < PAIRS; ++j) {
            const float e0 = __expf(vc[j].x);
            const float e1 = __expf(vc[j].y);
            const float e2 = __expf(vc[j].z);
            const float e3 = __expf(vc[j].w);
            float s = (e0 + e1) + (e2 + e3);
            s = sum32(s);

            const float thr   = PROB_THRESH * s;             // p>0.2  <=>  e>0.2*s
            const float inv_s = __builtin_amdgcn_rcpf(s);
            const float logZ  = __logf(s);

            if ((labc[j] >> 2) == sub) {
                const float xl = (labc[j] & 2) ? ((labc[j] & 1) ? vc[j].w : vc[j].z)
                                               : ((labc[j] & 1) ? vc[j].y : vc[j].x);
                base_acc += logZ - xl;
            }

            // penalty: cwp==0 kills excluded elements; only the e>thr mask remains
            float ps = 0.0f;
            ps = fmaf(w[j].x, (e0 > thr) ? e0 : 0.0f, ps);
            ps = fmaf(w[j].y, (e1 > thr) ? e1 : 0.0f, ps);
            ps = fmaf(w[j].z, (e2 > thr) ? e2 : 0.0f, ps);
            ps = fmaf(w[j].w, (e3 > thr) ? e3 : 0.0f, ps);
            pen_acc = fmaf(ps, inv_s, pen_acc);

            cnt_acc += ((w[j].x != 0.0f) && (e0 > thr)) ? 1.0f : 0.0f;
            cnt_acc += ((w[j].y != 0.0f) && (e1 > thr)) ? 1.0f : 0.0f;
            cnt_acc += ((w[j].z != 0.0f) && (e2 > thr)) ? 1.0f : 0.0f;
            cnt_acc += ((w[j].w != 0.0f) && (e3 > thr)) ? 1.0f : 0.0f;
        }

        // ---- rotate pipeline registers ----
        if (it + 1 < ITERS) {
            #pragma unroll
            for (int j = 0; j < PAIRS; ++j) { vc[j] = vn[j]; labc[j] = labn[j]; }
            if (it + 2 < ITERS) {
                #pragma unroll
                for (int j = 0; j < PAIRS; ++j) labn[j] = lab2[j];
            }
        }
    }

    // ---- wave + block reduction ----
    #pragma unroll
    for (int off = 32; off >= 1; off >>= 1) {
        base_acc += __shfl_xor(base_acc, off);
        pen_acc  += __shfl_xor(pen_acc, off);
        cnt_acc  += __shfl_xor(cnt_acc, off);
    }

    __shared__ float s_base[WPB], s_pen[WPB], s_cnt[WPB];
    if (lane == 0) { s_base[wave] = base_acc; s_pen[wave] = pen_acc; s_cnt[wave] = cnt_acc; }
    __syncthreads();
    if (threadIdx.x == 0) {
        float b = 0.0f, pn = 0.0f, c = 0.0f;
        #pragma unroll
        for (int i = 0; i < WPB; ++i) { b += s_base[i]; pn += s_pen[i]; c += s_cnt[i]; }
        partial[3 * blockIdx.x + 0] = b;
        partial[3 * blockIdx.x + 1] = pn;
        partial[3 * blockIdx.x + 2] = c;
    }
}

__global__ __launch_bounds__(256) void afl_finalize(
    const float* __restrict__ partial, float* __restrict__ out) {
    float b = 0.0f, pn = 0.0f, c = 0.0f;
    for (int i = threadIdx.x; i < BLOCKS; i += 256) {
        b  += partial[3 * i + 0];
        pn += partial[3 * i + 1];
        c  += partial[3 * i + 2];
    }
    #pragma unroll
    for (int off = 32; off >= 1; off >>= 1) {
        b  += __shfl_xor(b, off);
        pn += __shfl_xor(pn, off);
        c  += __shfl_xor(c, off);
    }
    __shared__ float sb[4], sp[4], sc[4];
    const int wave = threadIdx.x >> 6;
    if ((threadIdx.x & 63) == 0) { sb[wave] = b; sp[wave] = pn; sc[wave] = c; }
    __syncthreads();
    if (threadIdx.x == 0) {
        b  = sb[0] + sb[1] + sb[2] + sb[3];
        pn = sp[0] + sp[1] + sp[2] + sp[3];
        c  = sc[0] + sc[1] + sc[2] + sc[3];
        const float penalty = (c > 0.0f) ? (pn / c) : 0.0f;
        out[0] = b * (1.0f / (float)B_ROWS) + CONF_PEN * penalty;
    }
}

extern "C" void kernel_launch(void* const* d_in, const int* in_sizes, int n_in,
                              void* d_out, int out_size, void* d_ws, size_t ws_size,
                              hipStream_t stream) {
    const float* outputs = (const float*)d_in[0];
    const int*   labels  = (const int*)d_in[1];
    const float* cw      = (const float*)d_in[2];
    float* out     = (float*)d_out;
    float* partial = (float*)d_ws;
    float* cwp     = (float*)d_ws + 16384;   // 64 KB table past the partials

    afl_prep<<<(C_CLS * C_CLS) / THREADS, THREADS, 0, stream>>>(cw, cwp);
    afl_main<<<BLOCKS, THREADS, 0, stream>>>(outputs, labels, cwp, partial);
    afl_finalize<<<1, 256, 0, stream>>>(partial, out);
}